// Round 17
// baseline (2327.616 us; speedup 1.0000x reference)
//
#include <hip/hip_runtime.h>
#include <hip/hip_bf16.h>

// VanillaMPNN on MI355X — round 17: single-wave workgroups for edge/node.
// r16 showed edge OccupancyPercent=35% despite VGPR 64 / LDS 0 (allocation
// permits 100%). Theory: 4-wave blocks retire at block granularity; variance
// in per-wave tile counts strands CU slots. 64-thread blocks (1 wave each)
// let the scheduler backfill per-wave -> more waves in flight -> more MLP on
// the latency-bound gather. No algorithmic change vs r16 otherwise.

#define NE 48
#define NB_SH 8                       // 256 nodes per bucket

typedef __attribute__((ext_vector_type(8))) short short8;
typedef __attribute__((ext_vector_type(4))) float floatx4;

__device__ __forceinline__ unsigned short bf16_rne(float v) {
    unsigned u = __float_as_uint(v);
    u += 0x7FFFu + ((u >> 16) & 1u);
    return (unsigned short)(u >> 16);
}

// packed hi/lo split: 8 fp32 -> 8 bf16 hi + 8 bf16 lo (RNE both)
__device__ __forceinline__ void split8p(const float* __restrict__ x, short8& hi, short8& lo) {
    union { unsigned u[4]; short8 s; } H, L;
#pragma unroll
    for (int i = 0; i < 4; ++i) {
        float a = x[2 * i], b = x[2 * i + 1];
        __hip_bfloat162 h2 = __float22bfloat162_rn(make_float2(a, b));
        unsigned h = *reinterpret_cast<unsigned*>(&h2);
        float ra = a - __uint_as_float(h << 16);
        float rb = b - __uint_as_float(h & 0xFFFF0000u);
        __hip_bfloat162 l2 = __float22bfloat162_rn(make_float2(ra, rb));
        H.u[i] = h;
        L.u[i] = *reinterpret_cast<unsigned*>(&l2);
    }
    hi = H.s; lo = L.s;
}

// 3 j-tiles, 6 MFMA each: acc[t] = split3(A) @ B[t]
__device__ __forceinline__ void gemm3(const short8& ah0, const short8& al0,
                                      const short8& ah1, const short8& al1,
                                      const short8* __restrict__ hi,
                                      const short8* __restrict__ lo,
                                      int lane, floatx4* acc) {
#pragma unroll
    for (int t = 0; t < 3; ++t) {
        short8 bh0 = hi[(t * 2 + 0) * 64 + lane];
        short8 bh1 = hi[(t * 2 + 1) * 64 + lane];
        short8 bl0 = lo[(t * 2 + 0) * 64 + lane];
        short8 bl1 = lo[(t * 2 + 1) * 64 + lane];
        floatx4 c = {0.0f, 0.0f, 0.0f, 0.0f};
        c = __builtin_amdgcn_mfma_f32_16x16x32_bf16(ah0, bh0, c, 0, 0, 0);
        c = __builtin_amdgcn_mfma_f32_16x16x32_bf16(ah1, bh1, c, 0, 0, 0);
        c = __builtin_amdgcn_mfma_f32_16x16x32_bf16(al0, bh0, c, 0, 0, 0);
        c = __builtin_amdgcn_mfma_f32_16x16x32_bf16(al1, bh1, c, 0, 0, 0);
        c = __builtin_amdgcn_mfma_f32_16x16x32_bf16(ah0, bl0, c, 0, 0, 0);
        c = __builtin_amdgcn_mfma_f32_16x16x32_bf16(ah1, bl1, c, 0, 0, 0);
        acc[t] = c;
    }
}

// ---------------- embed ----------------
__global__ __launch_bounds__(256) void embed_kernel(const int* __restrict__ an,
                                                    const float* __restrict__ emb,
                                                    float* __restrict__ h, int n4) {
    int i = blockIdx.x * 256 + threadIdx.x;
    if (i >= n4) return;
    int n = i / 12, q = i - n * 12;
    ((float4*)h)[i] = ((const float4*)emb)[an[n] * 12 + q];
}

// ---------------- CSR build ----------------
__global__ __launch_bounds__(256) void hist_kernel(const int* __restrict__ dst,
                                                   int* __restrict__ cnt, int E) {
    int e = blockIdx.x * 256 + threadIdx.x;
    if (e < E) atomicAdd(&cnt[dst[e]], 1);
}

__global__ __launch_bounds__(256) void scansum_kernel(const int* __restrict__ cnt,
                                                      int* __restrict__ bsum, int N) {
    __shared__ int sw[4];
    const int tid = threadIdx.x, lane = tid & 63, wid = tid >> 6;
    int base = blockIdx.x * 1024;
    int v = 0;
#pragma unroll
    for (int k = 0; k < 4; ++k) {
        int i = base + k * 256 + tid;
        v += (i < N) ? cnt[i] : 0;
    }
#pragma unroll
    for (int o = 1; o < 64; o <<= 1) v += __shfl_xor(v, o, 64);
    if (lane == 0) sw[wid] = v;
    __syncthreads();
    if (tid == 0) bsum[blockIdx.x] = sw[0] + sw[1] + sw[2] + sw[3];
}

__global__ __launch_bounds__(256) void scanb_kernel(int* __restrict__ bsum, int nblk) {
    __shared__ int s[256];
    int tid = threadIdx.x;
    s[tid] = (tid < nblk) ? bsum[tid] : 0;
    __syncthreads();
    if (tid == 0) {
        int run = 0;
        for (int i = 0; i < nblk; ++i) { int t = s[i]; s[i] = run; run += t; }
    }
    __syncthreads();
    if (tid < nblk) bsum[tid] = s[tid];
}

__global__ __launch_bounds__(1024) void scanfix_kernel(const int* __restrict__ cnt,
                                                       const int* __restrict__ bsum,
                                                       int* __restrict__ offs,
                                                       int* __restrict__ gpos, int N) {
    __shared__ int swave[16];
    const int tid = threadIdx.x, lane = tid & 63, wid = tid >> 6;
    int i = blockIdx.x * 1024 + tid;
    int orig = (i < N) ? cnt[i] : 0;
    int v = orig;
#pragma unroll
    for (int off = 1; off < 64; off <<= 1) {
        int u = __shfl_up(v, off, 64);
        if (lane >= off) v += u;
    }
    if (lane == 63) swave[wid] = v;
    __syncthreads();
    if (wid == 0) {
        int w = (lane < 16) ? swave[lane] : 0;
#pragma unroll
        for (int off = 1; off < 16; off <<= 1) {
            int u = __shfl_up(w, off, 64);
            if (lane >= off) w += u;
        }
        if (lane < 16) swave[lane] = w;
    }
    __syncthreads();
    int prefix = (wid > 0) ? swave[wid - 1] : 0;
    int val = bsum[blockIdx.x] + prefix + v - orig;
    if (i < N) {
        offs[i] = val;
        if ((i & 255) == 0) gpos[i >> 8] = val;
    }
}

__global__ __launch_bounds__(256) void partA_kernel(const int* __restrict__ src,
                                                    const int* __restrict__ dst,
                                                    int* __restrict__ gpos,
                                                    int2* __restrict__ pairbuf,
                                                    int E, int NB) {
    __shared__ int lhist[512];
    __shared__ int lbase[512];
    const int tid = threadIdx.x;
    for (int i = tid; i < NB; i += 256) lhist[i] = 0;
    __syncthreads();
    const int base = blockIdx.x * 2048;
    int ssrc[8], sdst[8], rnk[8];
#pragma unroll
    for (int k = 0; k < 8; ++k) {
        int e = base + k * 256 + tid;
        if (e < E) {
            ssrc[k] = src[e]; sdst[k] = dst[e];
            rnk[k] = atomicAdd(&lhist[sdst[k] >> NB_SH], 1);
        }
    }
    __syncthreads();
    for (int i = tid; i < NB; i += 256) {
        int c = lhist[i];
        lbase[i] = c ? atomicAdd(&gpos[i], c) : 0;
    }
    __syncthreads();
#pragma unroll
    for (int k = 0; k < 8; ++k) {
        int e = base + k * 256 + tid;
        if (e < E)
            pairbuf[lbase[sdst[k] >> NB_SH] + rnk[k]] = make_int2(ssrc[k], sdst[k]);
    }
}

__global__ __launch_bounds__(256) void partB_kernel(const int2* __restrict__ pairbuf,
                                                    int* __restrict__ offs,   // becomes END offsets
                                                    int* __restrict__ colsrc, int E) {
    int e = blockIdx.x * 256 + threadIdx.x;
    if (e < E) {
        int2 p = pairbuf[e];
        int pos = atomicAdd(&offs[p.y], 1);
        colsrc[pos] = p.x;
    }
}

// ---------------- pack all 5 weight matrices -> B-fragment tables ----------------
__global__ __launch_bounds__(256) void pack_all_kernel(const float* __restrict__ w0,
                                                       const float* __restrict__ w1m,
                                                       const float* __restrict__ w2m,
                                                       const float* __restrict__ w3m,
                                                       const float* __restrict__ w4m,
                                                       short8* __restrict__ hi,
                                                       short8* __restrict__ lo) {
    int idx = blockIdx.x * 256 + threadIdx.x;
    if (idx >= 4 * 2304 + 384) return;
    int slot = idx / 2304;
    int rem  = idx - slot * 2304;
    const float* w = (slot == 0) ? w0 : (slot == 1) ? w1m : (slot == 2) ? w2m
                   : (slot == 3) ? w3m : w4m;
    int lane = rem & 63;
    int s = (rem >> 6) & 1;
    int t = (rem >> 7) % 3;
    int l = (rem >> 7) / 3;
    short8 h8, l8;
#pragma unroll
    for (int i = 0; i < 8; ++i) {
        int k = s * 32 + (lane >> 4) * 8 + i;
        int j = t * 16 + (lane & 15);
        float v = (k < NE) ? w[l * NE * NE + k * NE + j] : 0.0f;
        unsigned short hh = bf16_rne(v);
        float hf = __uint_as_float((unsigned)hh << 16);
        unsigned short ll = bf16_rne(v - hf);
        h8[i] = (short)hh;
        l8[i] = (short)ll;
    }
    hi[idx] = h8;
    lo[idx] = l8;
}

// ---------------- edge: node-centric MFMA, 4 nodes/wave, 1 wave/block ----------------
__global__ __launch_bounds__(64, 8) void edge_kernel(
    const float* __restrict__ hin,
    const int* __restrict__ colsrc,
    const int* __restrict__ ends,
    const int* __restrict__ cnt,
    float* __restrict__ tagg,                     // == hout, fully overwritten
    const short8* __restrict__ bhi,               // this layer's [3][2][64]
    const short8* __restrict__ blo,
    const float* __restrict__ b1,
    int N)
{
    const int lane = threadIdx.x;                 // 64-thread block = one wave
    const int n0 = blockIdx.x * 4;                // 4 consecutive nodes per wave
    if (n0 >= N) return;

    const int m  = lane & 15;
    const int kb = lane >> 4;

    short8 bh[6], bl[6];
#pragma unroll
    for (int i = 0; i < 6; ++i) { bh[i] = bhi[i * 64 + lane]; bl[i] = blo[i * 64 + lane]; }
    const float bb0 = b1[m], bb1 = b1[16 + m], bb2 = b1[32 + m];

#pragma unroll 1
    for (int nn = 0; nn < 4; ++nn) {
        const int n = n0 + nn;
        const int deg = cnt[n];
        const int end = ends[n];
        const int beg = end - deg;

        const float* hd = hin + (size_t)n * NE;
        float4 d0a = ((const float4*)(hd + kb * 8))[0];
        float4 d0b = ((const float4*)(hd + kb * 8))[1];
        float4 d1a = make_float4(0, 0, 0, 0), d1b = d1a;
        if (kb < 2) {
            d1a = ((const float4*)(hd + 32 + kb * 8))[0];
            d1b = ((const float4*)(hd + 32 + kb * 8))[1];
        }

        float s0 = 0.0f, s1 = 0.0f, s2 = 0.0f;
        const int ntile = (deg + 15) >> 4;

        for (int it = 0; it < ntile; ++it) {
            const int rem = deg - it * 16;
            int eidx = beg + it * 16 + m;
            int srow = colsrc[(m < rem) ? eidx : beg];
            const float* hs = hin + (size_t)srow * NE + kb * 8;

            float x0[8], x1[8];
            {
                float4 a0 = ((const float4*)hs)[0];
                float4 a1 = ((const float4*)hs)[1];
                x0[0] = a0.x * d0a.x; x0[1] = a0.y * d0a.y; x0[2] = a0.z * d0a.z; x0[3] = a0.w * d0a.w;
                x0[4] = a1.x * d0b.x; x0[5] = a1.y * d0b.y; x0[6] = a1.z * d0b.z; x0[7] = a1.w * d0b.w;
            }
            if (kb < 2) {
                float4 a0 = ((const float4*)(hs + 32))[0];
                float4 a1 = ((const float4*)(hs + 32))[1];
                x1[0] = a0.x * d1a.x; x1[1] = a0.y * d1a.y; x1[2] = a0.z * d1a.z; x1[3] = a0.w * d1a.w;
                x1[4] = a1.x * d1b.x; x1[5] = a1.y * d1b.y; x1[6] = a1.z * d1b.z; x1[7] = a1.w * d1b.w;
            } else {
#pragma unroll
                for (int i = 0; i < 8; ++i) x1[i] = 0.0f;
            }

            short8 ah0, al0, ah1, al1;
            split8p(x0, ah0, al0);
            split8p(x1, ah1, al1);

#pragma unroll
            for (int t = 0; t < 3; ++t) {
                short8 bh0 = bh[t * 2 + 0], bh1 = bh[t * 2 + 1];
                short8 bl0 = bl[t * 2 + 0], bl1 = bl[t * 2 + 1];
                floatx4 c = {0.0f, 0.0f, 0.0f, 0.0f};
                c = __builtin_amdgcn_mfma_f32_16x16x32_bf16(ah0, bh0, c, 0, 0, 0);
                c = __builtin_amdgcn_mfma_f32_16x16x32_bf16(ah1, bh1, c, 0, 0, 0);
                c = __builtin_amdgcn_mfma_f32_16x16x32_bf16(al0, bh0, c, 0, 0, 0);
                c = __builtin_amdgcn_mfma_f32_16x16x32_bf16(al1, bh1, c, 0, 0, 0);
                c = __builtin_amdgcn_mfma_f32_16x16x32_bf16(ah0, bl0, c, 0, 0, 0);
                c = __builtin_amdgcn_mfma_f32_16x16x32_bf16(ah1, bl1, c, 0, 0, 0);
                const float bb = (t == 0) ? bb0 : (t == 1) ? bb1 : bb2;
                float ts = 0.0f;
#pragma unroll
                for (int r = 0; r < 4; ++r) {
                    float v = fmaxf(c[r] + bb, 0.0f);
                    v = (kb * 4 + r < rem) ? v : 0.0f;
                    ts += v;
                }
                if (t == 0) s0 += ts; else if (t == 1) s1 += ts; else s2 += ts;
            }
        }

        s0 += __shfl_xor(s0, 16, 64); s0 += __shfl_xor(s0, 32, 64);
        s1 += __shfl_xor(s1, 16, 64); s1 += __shfl_xor(s1, 32, 64);
        s2 += __shfl_xor(s2, 16, 64); s2 += __shfl_xor(s2, 32, 64);

        float t1 = __shfl(s1, lane & 15, 64);
        float t2 = __shfl(s2, lane & 15, 64);
        float val = (lane < 16) ? s0 : (lane < 32) ? t1 : t2;
        if (lane < 48) tagg[(size_t)n * NE + lane] = val;
    }
}

// ---------------- node: 3 chained MFMA GEMMs; final layer fuses readout ----------------
__global__ __launch_bounds__(64, 8) void node_kernel(
    const float* __restrict__ hin,
    float* __restrict__ hout,                     // holds tagg on entry
    const int* __restrict__ cnt,
    const short8* __restrict__ w2hi, const short8* __restrict__ w2lo, const float* __restrict__ b2,
    const short8* __restrict__ u1hi, const short8* __restrict__ u1lo, const float* __restrict__ ub1,
    const short8* __restrict__ u2hi, const short8* __restrict__ u2lo, const float* __restrict__ ub2,
    int N,
    int final_layer,
    const int* __restrict__ gid,
    const short8* __restrict__ rw1hi, const short8* __restrict__ rw1lo,
    const float* __restrict__ rb1, const float* __restrict__ rw2,
    const float* __restrict__ rb2, float* __restrict__ out)
{
    __shared__ float tile[16][52];                // one wave per block
    const int lane = threadIdx.x;
    const int n0 = blockIdx.x * 16;
    if (n0 >= N) return;

    const int m  = lane & 15;
    const int kb = lane >> 4;

    float c0[8], c1[8];
    {
        const float* tg = hout + (size_t)(n0 + m) * NE;
        *(float4*)(c0)     = *(const float4*)(tg + kb * 8);
        *(float4*)(c0 + 4) = *(const float4*)(tg + kb * 8 + 4);
        if (kb < 2) {
            *(float4*)(c1)     = *(const float4*)(tg + 32 + kb * 8);
            *(float4*)(c1 + 4) = *(const float4*)(tg + 32 + kb * 8 + 4);
        } else {
#pragma unroll
            for (int i = 0; i < 8; ++i) c1[i] = 0.0f;
        }
    }
    short8 ah0, al0, ah1, al1;
    split8p(c0, ah0, al0);
    split8p(c1, ah1, al1);

    floatx4 acc[3];
    gemm3(ah0, al0, ah1, al1, w2hi, w2lo, lane, acc);   // tagg @ W2

    {
        float b2j[3];
#pragma unroll
        for (int t = 0; t < 3; ++t) b2j[t] = b2[t * 16 + m];
#pragma unroll
        for (int r = 0; r < 4; ++r) {
            float fd = (float)cnt[n0 + kb * 4 + r];
#pragma unroll
            for (int t = 0; t < 3; ++t) acc[t][r] = fmaf(fd, b2j[t], acc[t][r]);
        }
    }

    // transpose C->A, GEMM2: relu(agg @ U1 + ub1)
#pragma unroll
    for (int t = 0; t < 3; ++t)
#pragma unroll
        for (int r = 0; r < 4; ++r)
            tile[kb * 4 + r][t * 16 + m] = acc[t][r];
    asm volatile("s_waitcnt lgkmcnt(0)" ::: "memory");
    {
        const float* row = &tile[m][0];
        *(float4*)(c0)     = *(const float4*)(row + kb * 8);
        *(float4*)(c0 + 4) = *(const float4*)(row + kb * 8 + 4);
        if (kb < 2) {
            *(float4*)(c1)     = *(const float4*)(row + 32 + kb * 8);
            *(float4*)(c1 + 4) = *(const float4*)(row + 32 + kb * 8 + 4);
        } else {
#pragma unroll
            for (int i = 0; i < 8; ++i) c1[i] = 0.0f;
        }
    }
    asm volatile("s_waitcnt lgkmcnt(0)" ::: "memory");
    split8p(c0, ah0, al0);
    split8p(c1, ah1, al1);
    gemm3(ah0, al0, ah1, al1, u1hi, u1lo, lane, acc);
    {
        float bj[3];
#pragma unroll
        for (int t = 0; t < 3; ++t) bj[t] = ub1[t * 16 + m];
#pragma unroll
        for (int t = 0; t < 3; ++t)
#pragma unroll
            for (int r = 0; r < 4; ++r)
                acc[t][r] = fmaxf(acc[t][r] + bj[t], 0.0f);
    }

    // transpose C->A, GEMM3: t @ U2
#pragma unroll
    for (int t = 0; t < 3; ++t)
#pragma unroll
        for (int r = 0; r < 4; ++r)
            tile[kb * 4 + r][t * 16 + m] = acc[t][r];
    asm volatile("s_waitcnt lgkmcnt(0)" ::: "memory");
    {
        const float* row = &tile[m][0];
        *(float4*)(c0)     = *(const float4*)(row + kb * 8);
        *(float4*)(c0 + 4) = *(const float4*)(row + kb * 8 + 4);
        if (kb < 2) {
            *(float4*)(c1)     = *(const float4*)(row + 32 + kb * 8);
            *(float4*)(c1 + 4) = *(const float4*)(row + 32 + kb * 8 + 4);
        } else {
#pragma unroll
            for (int i = 0; i < 8; ++i) c1[i] = 0.0f;
        }
    }
    asm volatile("s_waitcnt lgkmcnt(0)" ::: "memory");
    split8p(c0, ah0, al0);
    split8p(c1, ah1, al1);
    gemm3(ah0, al0, ah1, al1, u2hi, u2lo, lane, acc);

    // out_h = hin + ub2 + acc  (C layout in acc)
    {
        float bj[3];
#pragma unroll
        for (int t = 0; t < 3; ++t) bj[t] = ub2[t * 16 + m];
#pragma unroll
        for (int r = 0; r < 4; ++r) {
            const size_t row = (size_t)(n0 + kb * 4 + r) * NE;
#pragma unroll
            for (int t = 0; t < 3; ++t)
                acc[t][r] += hin[row + t * 16 + m] + bj[t];
        }
    }

    if (!final_layer) {
#pragma unroll
        for (int r = 0; r < 4; ++r) {
            const size_t row = (size_t)(n0 + kb * 4 + r) * NE;
#pragma unroll
            for (int t = 0; t < 3; ++t)
                hout[row + t * 16 + m] = acc[t][r];
        }
        return;
    }

    // fused readout: y = relu(h @ ro_w1 + rb1) . rw2 + rb2 ; segment-sum by gid
#pragma unroll
    for (int t = 0; t < 3; ++t)
#pragma unroll
        for (int r = 0; r < 4; ++r)
            tile[kb * 4 + r][t * 16 + m] = acc[t][r];
    asm volatile("s_waitcnt lgkmcnt(0)" ::: "memory");
    {
        const float* row = &tile[m][0];
        *(float4*)(c0)     = *(const float4*)(row + kb * 8);
        *(float4*)(c0 + 4) = *(const float4*)(row + kb * 8 + 4);
        if (kb < 2) {
            *(float4*)(c1)     = *(const float4*)(row + 32 + kb * 8);
            *(float4*)(c1 + 4) = *(const float4*)(row + 32 + kb * 8 + 4);
        } else {
#pragma unroll
            for (int i = 0; i < 8; ++i) c1[i] = 0.0f;
        }
    }
    split8p(c0, ah0, al0);
    split8p(c1, ah1, al1);
    gemm3(ah0, al0, ah1, al1, rw1hi, rw1lo, lane, acc);

    float p[4] = {0.0f, 0.0f, 0.0f, 0.0f};
    {
        float bj[3], wj[3];
#pragma unroll
        for (int t = 0; t < 3; ++t) { bj[t] = rb1[t * 16 + m]; wj[t] = rw2[t * 16 + m]; }
#pragma unroll
        for (int t = 0; t < 3; ++t)
#pragma unroll
            for (int r = 0; r < 4; ++r)
                p[r] = fmaf(fmaxf(acc[t][r] + bj[t], 0.0f), wj[t], p[r]);
    }
#pragma unroll
    for (int o = 1; o < 16; o <<= 1) {
#pragma unroll
        for (int r = 0; r < 4; ++r) p[r] += __shfl_xor(p[r], o, 16);
    }
    if (m == 0) {
        float b2v = rb2[0];
#pragma unroll
        for (int r = 0; r < 4; ++r) {
            int n = n0 + kb * 4 + r;
            atomicAdd(out + gid[n], p[r] + b2v);
        }
    }
}

extern "C" void kernel_launch(void* const* d_in, const int* in_sizes, int n_in,
                              void* d_out, int out_size, void* d_ws, size_t ws_size,
                              hipStream_t stream) {
    const int*   AtomicNum = (const int*)  d_in[0];
    const int*   Edge      = (const int*)  d_in[1];
    const int*   graph_id  = (const int*)  d_in[2];
    const float* emb       = (const float*)d_in[3];
    const float* msg_w1    = (const float*)d_in[4];
    const float* msg_b1    = (const float*)d_in[5];
    const float* msg_w2    = (const float*)d_in[6];
    const float* msg_b2    = (const float*)d_in[7];
    const float* upd_w1    = (const float*)d_in[8];
    const float* upd_b1    = (const float*)d_in[9];
    const float* upd_w2    = (const float*)d_in[10];
    const float* upd_b2    = (const float*)d_in[11];
    const float* ro_w1     = (const float*)d_in[12];
    const float* ro_b1     = (const float*)d_in[13];
    const float* ro_w2     = (const float*)d_in[14];
    const float* ro_b2     = (const float*)d_in[15];

    const int N = in_sizes[0];          // 100000 (divisible by 16)
    const int E = in_sizes[1] / 2;      // 1600000
    const int* src = Edge;
    const int* dst = Edge + E;
    const int NB = (N + 255) >> NB_SH;  // 391 dst-buckets
    const int NBLK = (N + 1023) / 1024; // 98 scan blocks

    // workspace layout (~46 MB); pairbuf aliases h2 (consumed before layer 0)
    float*  h    = (float*)d_ws;                       // N*48
    float*  h2   = h  + (size_t)N * NE;                // N*48
    int*    cnt  = (int*)(h2 + (size_t)N * NE);        // N
    int*    offs = cnt + N;                            // N (end offsets after partB)
    int*    colsrc = offs + N;                         // E
    short8* whi  = (short8*)(colsrc + E);              // 4*2304 + 384
    short8* wlo  = whi + (4 * 2304 + 384);
    int*    gpos = (int*)(wlo + (4 * 2304 + 384));     // NB
    int*    bsum = gpos + NB;                          // NBLK
    int2*   pairbuf = (int2*)h2;                       // E (aliases h2)

    hipMemsetAsync(d_out, 0, (size_t)out_size * sizeof(float), stream);
    hipMemsetAsync(cnt, 0, (size_t)N * sizeof(int), stream);

    int n4 = N * 12;
    embed_kernel<<<(n4 + 255) / 256, 256, 0, stream>>>(AtomicNum, emb, h, n4);

    hist_kernel<<<(E + 255) / 256, 256, 0, stream>>>(dst, cnt, E);
    scansum_kernel<<<NBLK, 256, 0, stream>>>(cnt, bsum, N);
    scanb_kernel<<<1, 256, 0, stream>>>(bsum, NBLK);
    scanfix_kernel<<<NBLK, 1024, 0, stream>>>(cnt, bsum, offs, gpos, N);
    partA_kernel<<<(E + 2047) / 2048, 256, 0, stream>>>(src, dst, gpos, pairbuf, E, NB);
    partB_kernel<<<(E + 255) / 256, 256, 0, stream>>>(pairbuf, offs, colsrc, E);

    pack_all_kernel<<<(4 * 2304 + 384 + 255) / 256, 256, 0, stream>>>(
        msg_w1, msg_w2, upd_w1, upd_w2, ro_w1, whi, wlo);

    const float* hin = h;
    float* hout = h2;
    for (int l = 0; l < 6; ++l) {
        edge_kernel<<<N / 4, 64, 0, stream>>>(
            hin, colsrc, offs, cnt, hout,
            whi + 0 * 2304 + (size_t)l * 384, wlo + 0 * 2304 + (size_t)l * 384,
            msg_b1 + (size_t)l * NE,
            N);
        node_kernel<<<N / 16, 64, 0, stream>>>(
            hin, hout, cnt,
            whi + 1 * 2304 + (size_t)l * 384, wlo + 1 * 2304 + (size_t)l * 384, msg_b2 + (size_t)l * NE,
            whi + 2 * 2304 + (size_t)l * 384, wlo + 2 * 2304 + (size_t)l * 384, upd_b1 + (size_t)l * NE,
            whi + 3 * 2304 + (size_t)l * 384, wlo + 3 * 2304 + (size_t)l * 384, upd_b2 + (size_t)l * NE,
            N,
            (l == 5) ? 1 : 0,
            graph_id,
            whi + 4 * 2304, wlo + 4 * 2304,
            ro_b1, ro_w2, ro_b2, (float*)d_out);
        const float* tmp = hin; hin = hout; hout = (float*)tmp;
    }
}

// Round 18
// 823.426 us; speedup vs baseline: 2.8267x; 2.8267x over previous
//
#include <hip/hip_runtime.h>
#include <hip/hip_bf16.h>

// VanillaMPNN on MI355X — round 18: single-wave blocks with a sane VGPR cap.
// r17 post-mortem: 1-wave blocks lifted occupancy 35->82% (theory confirmed)
// but __launch_bounds__(64,8) halved the register budget (32 arch VGPRs with
// the AGPR split) -> massive scratch spill (FETCH 913 MB, WRITE 468 MB).
// Fix: __launch_bounds__(64,4) -> 128 regs/wave, no spill, wave-granular
// scheduling retained. Everything else identical to r16.

#define NE 48
#define NB_SH 8                       // 256 nodes per bucket

typedef __attribute__((ext_vector_type(8))) short short8;
typedef __attribute__((ext_vector_type(4))) float floatx4;

__device__ __forceinline__ unsigned short bf16_rne(float v) {
    unsigned u = __float_as_uint(v);
    u += 0x7FFFu + ((u >> 16) & 1u);
    return (unsigned short)(u >> 16);
}

// packed hi/lo split: 8 fp32 -> 8 bf16 hi + 8 bf16 lo (RNE both)
__device__ __forceinline__ void split8p(const float* __restrict__ x, short8& hi, short8& lo) {
    union { unsigned u[4]; short8 s; } H, L;
#pragma unroll
    for (int i = 0; i < 4; ++i) {
        float a = x[2 * i], b = x[2 * i + 1];
        __hip_bfloat162 h2 = __float22bfloat162_rn(make_float2(a, b));
        unsigned h = *reinterpret_cast<unsigned*>(&h2);
        float ra = a - __uint_as_float(h << 16);
        float rb = b - __uint_as_float(h & 0xFFFF0000u);
        __hip_bfloat162 l2 = __float22bfloat162_rn(make_float2(ra, rb));
        H.u[i] = h;
        L.u[i] = *reinterpret_cast<unsigned*>(&l2);
    }
    hi = H.s; lo = L.s;
}

// 3 j-tiles, 6 MFMA each: acc[t] = split3(A) @ B[t]
__device__ __forceinline__ void gemm3(const short8& ah0, const short8& al0,
                                      const short8& ah1, const short8& al1,
                                      const short8* __restrict__ hi,
                                      const short8* __restrict__ lo,
                                      int lane, floatx4* acc) {
#pragma unroll
    for (int t = 0; t < 3; ++t) {
        short8 bh0 = hi[(t * 2 + 0) * 64 + lane];
        short8 bh1 = hi[(t * 2 + 1) * 64 + lane];
        short8 bl0 = lo[(t * 2 + 0) * 64 + lane];
        short8 bl1 = lo[(t * 2 + 1) * 64 + lane];
        floatx4 c = {0.0f, 0.0f, 0.0f, 0.0f};
        c = __builtin_amdgcn_mfma_f32_16x16x32_bf16(ah0, bh0, c, 0, 0, 0);
        c = __builtin_amdgcn_mfma_f32_16x16x32_bf16(ah1, bh1, c, 0, 0, 0);
        c = __builtin_amdgcn_mfma_f32_16x16x32_bf16(al0, bh0, c, 0, 0, 0);
        c = __builtin_amdgcn_mfma_f32_16x16x32_bf16(al1, bh1, c, 0, 0, 0);
        c = __builtin_amdgcn_mfma_f32_16x16x32_bf16(ah0, bl0, c, 0, 0, 0);
        c = __builtin_amdgcn_mfma_f32_16x16x32_bf16(ah1, bl1, c, 0, 0, 0);
        acc[t] = c;
    }
}

// ---------------- embed ----------------
__global__ __launch_bounds__(256) void embed_kernel(const int* __restrict__ an,
                                                    const float* __restrict__ emb,
                                                    float* __restrict__ h, int n4) {
    int i = blockIdx.x * 256 + threadIdx.x;
    if (i >= n4) return;
    int n = i / 12, q = i - n * 12;
    ((float4*)h)[i] = ((const float4*)emb)[an[n] * 12 + q];
}

// ---------------- CSR build ----------------
__global__ __launch_bounds__(256) void hist_kernel(const int* __restrict__ dst,
                                                   int* __restrict__ cnt, int E) {
    int e = blockIdx.x * 256 + threadIdx.x;
    if (e < E) atomicAdd(&cnt[dst[e]], 1);
}

__global__ __launch_bounds__(256) void scansum_kernel(const int* __restrict__ cnt,
                                                      int* __restrict__ bsum, int N) {
    __shared__ int sw[4];
    const int tid = threadIdx.x, lane = tid & 63, wid = tid >> 6;
    int base = blockIdx.x * 1024;
    int v = 0;
#pragma unroll
    for (int k = 0; k < 4; ++k) {
        int i = base + k * 256 + tid;
        v += (i < N) ? cnt[i] : 0;
    }
#pragma unroll
    for (int o = 1; o < 64; o <<= 1) v += __shfl_xor(v, o, 64);
    if (lane == 0) sw[wid] = v;
    __syncthreads();
    if (tid == 0) bsum[blockIdx.x] = sw[0] + sw[1] + sw[2] + sw[3];
}

__global__ __launch_bounds__(256) void scanb_kernel(int* __restrict__ bsum, int nblk) {
    __shared__ int s[256];
    int tid = threadIdx.x;
    s[tid] = (tid < nblk) ? bsum[tid] : 0;
    __syncthreads();
    if (tid == 0) {
        int run = 0;
        for (int i = 0; i < nblk; ++i) { int t = s[i]; s[i] = run; run += t; }
    }
    __syncthreads();
    if (tid < nblk) bsum[tid] = s[tid];
}

__global__ __launch_bounds__(1024) void scanfix_kernel(const int* __restrict__ cnt,
                                                       const int* __restrict__ bsum,
                                                       int* __restrict__ offs,
                                                       int* __restrict__ gpos, int N) {
    __shared__ int swave[16];
    const int tid = threadIdx.x, lane = tid & 63, wid = tid >> 6;
    int i = blockIdx.x * 1024 + tid;
    int orig = (i < N) ? cnt[i] : 0;
    int v = orig;
#pragma unroll
    for (int off = 1; off < 64; off <<= 1) {
        int u = __shfl_up(v, off, 64);
        if (lane >= off) v += u;
    }
    if (lane == 63) swave[wid] = v;
    __syncthreads();
    if (wid == 0) {
        int w = (lane < 16) ? swave[lane] : 0;
#pragma unroll
        for (int off = 1; off < 16; off <<= 1) {
            int u = __shfl_up(w, off, 64);
            if (lane >= off) w += u;
        }
        if (lane < 16) swave[lane] = w;
    }
    __syncthreads();
    int prefix = (wid > 0) ? swave[wid - 1] : 0;
    int val = bsum[blockIdx.x] + prefix + v - orig;
    if (i < N) {
        offs[i] = val;
        if ((i & 255) == 0) gpos[i >> 8] = val;
    }
}

__global__ __launch_bounds__(256) void partA_kernel(const int* __restrict__ src,
                                                    const int* __restrict__ dst,
                                                    int* __restrict__ gpos,
                                                    int2* __restrict__ pairbuf,
                                                    int E, int NB) {
    __shared__ int lhist[512];
    __shared__ int lbase[512];
    const int tid = threadIdx.x;
    for (int i = tid; i < NB; i += 256) lhist[i] = 0;
    __syncthreads();
    const int base = blockIdx.x * 2048;
    int ssrc[8], sdst[8], rnk[8];
#pragma unroll
    for (int k = 0; k < 8; ++k) {
        int e = base + k * 256 + tid;
        if (e < E) {
            ssrc[k] = src[e]; sdst[k] = dst[e];
            rnk[k] = atomicAdd(&lhist[sdst[k] >> NB_SH], 1);
        }
    }
    __syncthreads();
    for (int i = tid; i < NB; i += 256) {
        int c = lhist[i];
        lbase[i] = c ? atomicAdd(&gpos[i], c) : 0;
    }
    __syncthreads();
#pragma unroll
    for (int k = 0; k < 8; ++k) {
        int e = base + k * 256 + tid;
        if (e < E)
            pairbuf[lbase[sdst[k] >> NB_SH] + rnk[k]] = make_int2(ssrc[k], sdst[k]);
    }
}

__global__ __launch_bounds__(256) void partB_kernel(const int2* __restrict__ pairbuf,
                                                    int* __restrict__ offs,   // becomes END offsets
                                                    int* __restrict__ colsrc, int E) {
    int e = blockIdx.x * 256 + threadIdx.x;
    if (e < E) {
        int2 p = pairbuf[e];
        int pos = atomicAdd(&offs[p.y], 1);
        colsrc[pos] = p.x;
    }
}

// ---------------- pack all 5 weight matrices -> B-fragment tables ----------------
__global__ __launch_bounds__(256) void pack_all_kernel(const float* __restrict__ w0,
                                                       const float* __restrict__ w1m,
                                                       const float* __restrict__ w2m,
                                                       const float* __restrict__ w3m,
                                                       const float* __restrict__ w4m,
                                                       short8* __restrict__ hi,
                                                       short8* __restrict__ lo) {
    int idx = blockIdx.x * 256 + threadIdx.x;
    if (idx >= 4 * 2304 + 384) return;
    int slot = idx / 2304;
    int rem  = idx - slot * 2304;
    const float* w = (slot == 0) ? w0 : (slot == 1) ? w1m : (slot == 2) ? w2m
                   : (slot == 3) ? w3m : w4m;
    int lane = rem & 63;
    int s = (rem >> 6) & 1;
    int t = (rem >> 7) % 3;
    int l = (rem >> 7) / 3;
    short8 h8, l8;
#pragma unroll
    for (int i = 0; i < 8; ++i) {
        int k = s * 32 + (lane >> 4) * 8 + i;
        int j = t * 16 + (lane & 15);
        float v = (k < NE) ? w[l * NE * NE + k * NE + j] : 0.0f;
        unsigned short hh = bf16_rne(v);
        float hf = __uint_as_float((unsigned)hh << 16);
        unsigned short ll = bf16_rne(v - hf);
        h8[i] = (short)hh;
        l8[i] = (short)ll;
    }
    hi[idx] = h8;
    lo[idx] = l8;
}

// ---------------- edge: node-centric MFMA, 4 nodes/wave, 1 wave/block ----------------
__global__ __launch_bounds__(64, 4) void edge_kernel(
    const float* __restrict__ hin,
    const int* __restrict__ colsrc,
    const int* __restrict__ ends,
    const int* __restrict__ cnt,
    float* __restrict__ tagg,                     // == hout, fully overwritten
    const short8* __restrict__ bhi,               // this layer's [3][2][64]
    const short8* __restrict__ blo,
    const float* __restrict__ b1,
    int N)
{
    const int lane = threadIdx.x;                 // 64-thread block = one wave
    const int n0 = blockIdx.x * 4;                // 4 consecutive nodes per wave
    if (n0 >= N) return;

    const int m  = lane & 15;
    const int kb = lane >> 4;

    short8 bh[6], bl[6];
#pragma unroll
    for (int i = 0; i < 6; ++i) { bh[i] = bhi[i * 64 + lane]; bl[i] = blo[i * 64 + lane]; }
    const float bb0 = b1[m], bb1 = b1[16 + m], bb2 = b1[32 + m];

#pragma unroll 1
    for (int nn = 0; nn < 4; ++nn) {
        const int n = n0 + nn;
        const int deg = cnt[n];
        const int end = ends[n];
        const int beg = end - deg;

        const float* hd = hin + (size_t)n * NE;
        float4 d0a = ((const float4*)(hd + kb * 8))[0];
        float4 d0b = ((const float4*)(hd + kb * 8))[1];
        float4 d1a = make_float4(0, 0, 0, 0), d1b = d1a;
        if (kb < 2) {
            d1a = ((const float4*)(hd + 32 + kb * 8))[0];
            d1b = ((const float4*)(hd + 32 + kb * 8))[1];
        }

        float s0 = 0.0f, s1 = 0.0f, s2 = 0.0f;
        const int ntile = (deg + 15) >> 4;

        for (int it = 0; it < ntile; ++it) {
            const int rem = deg - it * 16;
            int eidx = beg + it * 16 + m;
            int srow = colsrc[(m < rem) ? eidx : beg];
            const float* hs = hin + (size_t)srow * NE + kb * 8;

            float x0[8], x1[8];
            {
                float4 a0 = ((const float4*)hs)[0];
                float4 a1 = ((const float4*)hs)[1];
                x0[0] = a0.x * d0a.x; x0[1] = a0.y * d0a.y; x0[2] = a0.z * d0a.z; x0[3] = a0.w * d0a.w;
                x0[4] = a1.x * d0b.x; x0[5] = a1.y * d0b.y; x0[6] = a1.z * d0b.z; x0[7] = a1.w * d0b.w;
            }
            if (kb < 2) {
                float4 a0 = ((const float4*)(hs + 32))[0];
                float4 a1 = ((const float4*)(hs + 32))[1];
                x1[0] = a0.x * d1a.x; x1[1] = a0.y * d1a.y; x1[2] = a0.z * d1a.z; x1[3] = a0.w * d1a.w;
                x1[4] = a1.x * d1b.x; x1[5] = a1.y * d1b.y; x1[6] = a1.z * d1b.z; x1[7] = a1.w * d1b.w;
            } else {
#pragma unroll
                for (int i = 0; i < 8; ++i) x1[i] = 0.0f;
            }

            short8 ah0, al0, ah1, al1;
            split8p(x0, ah0, al0);
            split8p(x1, ah1, al1);

#pragma unroll
            for (int t = 0; t < 3; ++t) {
                short8 bh0 = bh[t * 2 + 0], bh1 = bh[t * 2 + 1];
                short8 bl0 = bl[t * 2 + 0], bl1 = bl[t * 2 + 1];
                floatx4 c = {0.0f, 0.0f, 0.0f, 0.0f};
                c = __builtin_amdgcn_mfma_f32_16x16x32_bf16(ah0, bh0, c, 0, 0, 0);
                c = __builtin_amdgcn_mfma_f32_16x16x32_bf16(ah1, bh1, c, 0, 0, 0);
                c = __builtin_amdgcn_mfma_f32_16x16x32_bf16(al0, bh0, c, 0, 0, 0);
                c = __builtin_amdgcn_mfma_f32_16x16x32_bf16(al1, bh1, c, 0, 0, 0);
                c = __builtin_amdgcn_mfma_f32_16x16x32_bf16(ah0, bl0, c, 0, 0, 0);
                c = __builtin_amdgcn_mfma_f32_16x16x32_bf16(ah1, bl1, c, 0, 0, 0);
                const float bb = (t == 0) ? bb0 : (t == 1) ? bb1 : bb2;
                float ts = 0.0f;
#pragma unroll
                for (int r = 0; r < 4; ++r) {
                    float v = fmaxf(c[r] + bb, 0.0f);
                    v = (kb * 4 + r < rem) ? v : 0.0f;
                    ts += v;
                }
                if (t == 0) s0 += ts; else if (t == 1) s1 += ts; else s2 += ts;
            }
        }

        s0 += __shfl_xor(s0, 16, 64); s0 += __shfl_xor(s0, 32, 64);
        s1 += __shfl_xor(s1, 16, 64); s1 += __shfl_xor(s1, 32, 64);
        s2 += __shfl_xor(s2, 16, 64); s2 += __shfl_xor(s2, 32, 64);

        float t1 = __shfl(s1, lane & 15, 64);
        float t2 = __shfl(s2, lane & 15, 64);
        float val = (lane < 16) ? s0 : (lane < 32) ? t1 : t2;
        if (lane < 48) tagg[(size_t)n * NE + lane] = val;
    }
}

// ---------------- node: 3 chained MFMA GEMMs; final layer fuses readout ----------------
__global__ __launch_bounds__(64, 4) void node_kernel(
    const float* __restrict__ hin,
    float* __restrict__ hout,                     // holds tagg on entry
    const int* __restrict__ cnt,
    const short8* __restrict__ w2hi, const short8* __restrict__ w2lo, const float* __restrict__ b2,
    const short8* __restrict__ u1hi, const short8* __restrict__ u1lo, const float* __restrict__ ub1,
    const short8* __restrict__ u2hi, const short8* __restrict__ u2lo, const float* __restrict__ ub2,
    int N,
    int final_layer,
    const int* __restrict__ gid,
    const short8* __restrict__ rw1hi, const short8* __restrict__ rw1lo,
    const float* __restrict__ rb1, const float* __restrict__ rw2,
    const float* __restrict__ rb2, float* __restrict__ out)
{
    __shared__ float tile[16][52];                // one wave per block
    const int lane = threadIdx.x;
    const int n0 = blockIdx.x * 16;
    if (n0 >= N) return;

    const int m  = lane & 15;
    const int kb = lane >> 4;

    float c0[8], c1[8];
    {
        const float* tg = hout + (size_t)(n0 + m) * NE;
        *(float4*)(c0)     = *(const float4*)(tg + kb * 8);
        *(float4*)(c0 + 4) = *(const float4*)(tg + kb * 8 + 4);
        if (kb < 2) {
            *(float4*)(c1)     = *(const float4*)(tg + 32 + kb * 8);
            *(float4*)(c1 + 4) = *(const float4*)(tg + 32 + kb * 8 + 4);
        } else {
#pragma unroll
            for (int i = 0; i < 8; ++i) c1[i] = 0.0f;
        }
    }
    short8 ah0, al0, ah1, al1;
    split8p(c0, ah0, al0);
    split8p(c1, ah1, al1);

    floatx4 acc[3];
    gemm3(ah0, al0, ah1, al1, w2hi, w2lo, lane, acc);   // tagg @ W2

    {
        float b2j[3];
#pragma unroll
        for (int t = 0; t < 3; ++t) b2j[t] = b2[t * 16 + m];
#pragma unroll
        for (int r = 0; r < 4; ++r) {
            float fd = (float)cnt[n0 + kb * 4 + r];
#pragma unroll
            for (int t = 0; t < 3; ++t) acc[t][r] = fmaf(fd, b2j[t], acc[t][r]);
        }
    }

    // transpose C->A, GEMM2: relu(agg @ U1 + ub1)
#pragma unroll
    for (int t = 0; t < 3; ++t)
#pragma unroll
        for (int r = 0; r < 4; ++r)
            tile[kb * 4 + r][t * 16 + m] = acc[t][r];
    asm volatile("s_waitcnt lgkmcnt(0)" ::: "memory");
    {
        const float* row = &tile[m][0];
        *(float4*)(c0)     = *(const float4*)(row + kb * 8);
        *(float4*)(c0 + 4) = *(const float4*)(row + kb * 8 + 4);
        if (kb < 2) {
            *(float4*)(c1)     = *(const float4*)(row + 32 + kb * 8);
            *(float4*)(c1 + 4) = *(const float4*)(row + 32 + kb * 8 + 4);
        } else {
#pragma unroll
            for (int i = 0; i < 8; ++i) c1[i] = 0.0f;
        }
    }
    asm volatile("s_waitcnt lgkmcnt(0)" ::: "memory");
    split8p(c0, ah0, al0);
    split8p(c1, ah1, al1);
    gemm3(ah0, al0, ah1, al1, u1hi, u1lo, lane, acc);
    {
        float bj[3];
#pragma unroll
        for (int t = 0; t < 3; ++t) bj[t] = ub1[t * 16 + m];
#pragma unroll
        for (int t = 0; t < 3; ++t)
#pragma unroll
            for (int r = 0; r < 4; ++r)
                acc[t][r] = fmaxf(acc[t][r] + bj[t], 0.0f);
    }

    // transpose C->A, GEMM3: t @ U2
#pragma unroll
    for (int t = 0; t < 3; ++t)
#pragma unroll
        for (int r = 0; r < 4; ++r)
            tile[kb * 4 + r][t * 16 + m] = acc[t][r];
    asm volatile("s_waitcnt lgkmcnt(0)" ::: "memory");
    {
        const float* row = &tile[m][0];
        *(float4*)(c0)     = *(const float4*)(row + kb * 8);
        *(float4*)(c0 + 4) = *(const float4*)(row + kb * 8 + 4);
        if (kb < 2) {
            *(float4*)(c1)     = *(const float4*)(row + 32 + kb * 8);
            *(float4*)(c1 + 4) = *(const float4*)(row + 32 + kb * 8 + 4);
        } else {
#pragma unroll
            for (int i = 0; i < 8; ++i) c1[i] = 0.0f;
        }
    }
    asm volatile("s_waitcnt lgkmcnt(0)" ::: "memory");
    split8p(c0, ah0, al0);
    split8p(c1, ah1, al1);
    gemm3(ah0, al0, ah1, al1, u2hi, u2lo, lane, acc);

    // out_h = hin + ub2 + acc  (C layout in acc)
    {
        float bj[3];
#pragma unroll
        for (int t = 0; t < 3; ++t) bj[t] = ub2[t * 16 + m];
#pragma unroll
        for (int r = 0; r < 4; ++r) {
            const size_t row = (size_t)(n0 + kb * 4 + r) * NE;
#pragma unroll
            for (int t = 0; t < 3; ++t)
                acc[t][r] += hin[row + t * 16 + m] + bj[t];
        }
    }

    if (!final_layer) {
#pragma unroll
        for (int r = 0; r < 4; ++r) {
            const size_t row = (size_t)(n0 + kb * 4 + r) * NE;
#pragma unroll
            for (int t = 0; t < 3; ++t)
                hout[row + t * 16 + m] = acc[t][r];
        }
        return;
    }

    // fused readout: y = relu(h @ ro_w1 + rb1) . rw2 + rb2 ; segment-sum by gid
#pragma unroll
    for (int t = 0; t < 3; ++t)
#pragma unroll
        for (int r = 0; r < 4; ++r)
            tile[kb * 4 + r][t * 16 + m] = acc[t][r];
    asm volatile("s_waitcnt lgkmcnt(0)" ::: "memory");
    {
        const float* row = &tile[m][0];
        *(float4*)(c0)     = *(const float4*)(row + kb * 8);
        *(float4*)(c0 + 4) = *(const float4*)(row + kb * 8 + 4);
        if (kb < 2) {
            *(float4*)(c1)     = *(const float4*)(row + 32 + kb * 8);
            *(float4*)(c1 + 4) = *(const float4*)(row + 32 + kb * 8 + 4);
        } else {
#pragma unroll
            for (int i = 0; i < 8; ++i) c1[i] = 0.0f;
        }
    }
    split8p(c0, ah0, al0);
    split8p(c1, ah1, al1);
    gemm3(ah0, al0, ah1, al1, rw1hi, rw1lo, lane, acc);

    float p[4] = {0.0f, 0.0f, 0.0f, 0.0f};
    {
        float bj[3], wj[3];
#pragma unroll
        for (int t = 0; t < 3; ++t) { bj[t] = rb1[t * 16 + m]; wj[t] = rw2[t * 16 + m]; }
#pragma unroll
        for (int t = 0; t < 3; ++t)
#pragma unroll
            for (int r = 0; r < 4; ++r)
                p[r] = fmaf(fmaxf(acc[t][r] + bj[t], 0.0f), wj[t], p[r]);
    }
#pragma unroll
    for (int o = 1; o < 16; o <<= 1) {
#pragma unroll
        for (int r = 0; r < 4; ++r) p[r] += __shfl_xor(p[r], o, 16);
    }
    if (m == 0) {
        float b2v = rb2[0];
#pragma unroll
        for (int r = 0; r < 4; ++r) {
            int n = n0 + kb * 4 + r;
            atomicAdd(out + gid[n], p[r] + b2v);
        }
    }
}

extern "C" void kernel_launch(void* const* d_in, const int* in_sizes, int n_in,
                              void* d_out, int out_size, void* d_ws, size_t ws_size,
                              hipStream_t stream) {
    const int*   AtomicNum = (const int*)  d_in[0];
    const int*   Edge      = (const int*)  d_in[1];
    const int*   graph_id  = (const int*)  d_in[2];
    const float* emb       = (const float*)d_in[3];
    const float* msg_w1    = (const float*)d_in[4];
    const float* msg_b1    = (const float*)d_in[5];
    const float* msg_w2    = (const float*)d_in[6];
    const float* msg_b2    = (const float*)d_in[7];
    const float* upd_w1    = (const float*)d_in[8];
    const float* upd_b1    = (const float*)d_in[9];
    const float* upd_w2    = (const float*)d_in[10];
    const float* upd_b2    = (const float*)d_in[11];
    const float* ro_w1     = (const float*)d_in[12];
    const float* ro_b1     = (const float*)d_in[13];
    const float* ro_w2     = (const float*)d_in[14];
    const float* ro_b2     = (const float*)d_in[15];

    const int N = in_sizes[0];          // 100000 (divisible by 16)
    const int E = in_sizes[1] / 2;      // 1600000
    const int* src = Edge;
    const int* dst = Edge + E;
    const int NB = (N + 255) >> NB_SH;  // 391 dst-buckets
    const int NBLK = (N + 1023) / 1024; // 98 scan blocks

    // workspace layout (~46 MB); pairbuf aliases h2 (consumed before layer 0)
    float*  h    = (float*)d_ws;                       // N*48
    float*  h2   = h  + (size_t)N * NE;                // N*48
    int*    cnt  = (int*)(h2 + (size_t)N * NE);        // N
    int*    offs = cnt + N;                            // N (end offsets after partB)
    int*    colsrc = offs + N;                         // E
    short8* whi  = (short8*)(colsrc + E);              // 4*2304 + 384
    short8* wlo  = whi + (4 * 2304 + 384);
    int*    gpos = (int*)(wlo + (4 * 2304 + 384));     // NB
    int*    bsum = gpos + NB;                          // NBLK
    int2*   pairbuf = (int2*)h2;                       // E (aliases h2)

    hipMemsetAsync(d_out, 0, (size_t)out_size * sizeof(float), stream);
    hipMemsetAsync(cnt, 0, (size_t)N * sizeof(int), stream);

    int n4 = N * 12;
    embed_kernel<<<(n4 + 255) / 256, 256, 0, stream>>>(AtomicNum, emb, h, n4);

    hist_kernel<<<(E + 255) / 256, 256, 0, stream>>>(dst, cnt, E);
    scansum_kernel<<<NBLK, 256, 0, stream>>>(cnt, bsum, N);
    scanb_kernel<<<1, 256, 0, stream>>>(bsum, NBLK);
    scanfix_kernel<<<NBLK, 1024, 0, stream>>>(cnt, bsum, offs, gpos, N);
    partA_kernel<<<(E + 2047) / 2048, 256, 0, stream>>>(src, dst, gpos, pairbuf, E, NB);
    partB_kernel<<<(E + 255) / 256, 256, 0, stream>>>(pairbuf, offs, colsrc, E);

    pack_all_kernel<<<(4 * 2304 + 384 + 255) / 256, 256, 0, stream>>>(
        msg_w1, msg_w2, upd_w1, upd_w2, ro_w1, whi, wlo);

    const float* hin = h;
    float* hout = h2;
    for (int l = 0; l < 6; ++l) {
        edge_kernel<<<N / 4, 64, 0, stream>>>(
            hin, colsrc, offs, cnt, hout,
            whi + 0 * 2304 + (size_t)l * 384, wlo + 0 * 2304 + (size_t)l * 384,
            msg_b1 + (size_t)l * NE,
            N);
        node_kernel<<<N / 16, 64, 0, stream>>>(
            hin, hout, cnt,
            whi + 1 * 2304 + (size_t)l * 384, wlo + 1 * 2304 + (size_t)l * 384, msg_b2 + (size_t)l * NE,
            whi + 2 * 2304 + (size_t)l * 384, wlo + 2 * 2304 + (size_t)l * 384, upd_b1 + (size_t)l * NE,
            whi + 3 * 2304 + (size_t)l * 384, wlo + 3 * 2304 + (size_t)l * 384, upd_b2 + (size_t)l * NE,
            N,
            (l == 5) ? 1 : 0,
            graph_id,
            whi + 4 * 2304, wlo + 4 * 2304,
            ro_b1, ro_w2, ro_b2, (float*)d_out);
        const float* tmp = hin; hin = hout; hout = (float*)tmp;
    }
}